// Round 2
// baseline (439.090 us; speedup 1.0000x reference)
//
#include <hip/hip_runtime.h>
#include <math.h>

#define N_NODES 50000
#define N_EDGES 800000
#define HID 16

// ---------------------------------------------------------------------------
// degree: cnt[dst] += 1 for every edge (region mask does NOT apply to counts)
// ---------------------------------------------------------------------------
__global__ void degree_kernel(const int* __restrict__ dst, float* __restrict__ cnt) {
    int e = blockIdx.x * blockDim.x + threadIdx.x;
    if (e >= N_EDGES) return;
    atomicAdd(cnt + dst[e], 1.0f);
}

// ---------------------------------------------------------------------------
// edge message: msg[e,j] = sum_c h[src][c] * relu(rel . Win[:, c*16+j] + bin)
// scatter-add into agg[dst]. Skipped entirely when regions differ (~90%).
// ---------------------------------------------------------------------------
template <int IN_C>
__global__ void edge_msg_kernel(const float* __restrict__ x,        // pos: x[n*16+0..1]
                                const float* __restrict__ hbase,    // h source, stride 16
                                const int* __restrict__ src,
                                const int* __restrict__ dst,
                                const int* __restrict__ region,
                                const float* __restrict__ Win,      // (2, IN_C*16) row-major
                                const float* __restrict__ bin,      // (IN_C*16)
                                float* __restrict__ agg) {
    int e = blockIdx.x * blockDim.x + threadIdx.x;
    if (e >= N_EDGES) return;
    int s = src[e];
    int d = dst[e];
    if (region[s] != region[d]) return;

    float rx = x[d * 16 + 0] - x[s * 16 + 0];
    float ry = x[d * 16 + 1] - x[s * 16 + 1];

    const float* hs = hbase + s * 16;
    float msg[HID];
#pragma unroll
    for (int j = 0; j < HID; ++j) msg[j] = 0.0f;

#pragma unroll
    for (int c = 0; c < IN_C; ++c) {
        float hc = hs[c];
#pragma unroll
        for (int j = 0; j < HID; ++j) {
            float sp = fmaf(rx, Win[c * HID + j],
                       fmaf(ry, Win[IN_C * HID + c * HID + j], bin[c * HID + j]));
            sp = fmaxf(sp, 0.0f);
            msg[j] = fmaf(hc, sp, msg[j]);
        }
    }

    float* ag = agg + d * HID;
#pragma unroll
    for (int j = 0; j < HID; ++j) atomicAdd(ag + j, msg[j]);
}

// ---------------------------------------------------------------------------
// node update: h_out = relu((agg / max(cnt,1)) @ Wout + bout)
// ---------------------------------------------------------------------------
__global__ void node_update_kernel(const float* __restrict__ agg,
                                   const float* __restrict__ cnt,
                                   const float* __restrict__ Wout,  // (16,16) row-major
                                   const float* __restrict__ bout,  // (16)
                                   float* __restrict__ hout) {
    int n = blockIdx.x * blockDim.x + threadIdx.x;
    if (n >= N_NODES) return;
    float inv = 1.0f / fmaxf(cnt[n], 1.0f);

    float a[HID];
    const float4* ap = (const float4*)(agg + n * HID);
#pragma unroll
    for (int q = 0; q < 4; ++q) {
        float4 v = ap[q];
        a[q * 4 + 0] = v.x * inv;
        a[q * 4 + 1] = v.y * inv;
        a[q * 4 + 2] = v.z * inv;
        a[q * 4 + 3] = v.w * inv;
    }

    float o[HID];
#pragma unroll
    for (int j = 0; j < HID; ++j) o[j] = bout[j];
#pragma unroll
    for (int c = 0; c < HID; ++c) {
        float ac = a[c];
#pragma unroll
        for (int j = 0; j < HID; ++j) o[j] = fmaf(ac, Wout[c * HID + j], o[j]);
    }

    float4* hp = (float4*)(hout + n * HID);
#pragma unroll
    for (int q = 0; q < 4; ++q) {
        float4 v;
        v.x = fmaxf(o[q * 4 + 0], 0.0f);
        v.y = fmaxf(o[q * 4 + 1], 0.0f);
        v.z = fmaxf(o[q * 4 + 2], 0.0f);
        v.w = fmaxf(o[q * 4 + 3], 0.0f);
        hp[q] = v;
    }
}

// ---------------------------------------------------------------------------
// decoder: z=[h[src],h[dst]] (32) -> relu(z@Wd1+b1) -> relu(@Wd2+b2) -> sigmoid(@Wd3+b3)
// ---------------------------------------------------------------------------
__global__ void decoder_kernel(const float* __restrict__ h,
                               const int* __restrict__ src,
                               const int* __restrict__ dst,
                               const float* __restrict__ Wd1,  // (32,16)
                               const float* __restrict__ bd1,  // (16)
                               const float* __restrict__ Wd2,  // (16,16)
                               const float* __restrict__ bd2,  // (16)
                               const float* __restrict__ Wd3,  // (16,1)
                               const float* __restrict__ bd3,  // (1)
                               float* __restrict__ out) {
    int e = blockIdx.x * blockDim.x + threadIdx.x;
    if (e >= N_EDGES) return;
    int s = src[e];
    int d = dst[e];

    float z[32];
    const float4* hs = (const float4*)(h + s * HID);
    const float4* hd = (const float4*)(h + d * HID);
#pragma unroll
    for (int q = 0; q < 4; ++q) {
        float4 v = hs[q];
        z[q * 4 + 0] = v.x; z[q * 4 + 1] = v.y; z[q * 4 + 2] = v.z; z[q * 4 + 3] = v.w;
    }
#pragma unroll
    for (int q = 0; q < 4; ++q) {
        float4 v = hd[q];
        z[16 + q * 4 + 0] = v.x; z[16 + q * 4 + 1] = v.y; z[16 + q * 4 + 2] = v.z; z[16 + q * 4 + 3] = v.w;
    }

    float d1[HID];
#pragma unroll
    for (int j = 0; j < HID; ++j) d1[j] = bd1[j];
#pragma unroll
    for (int c = 0; c < 32; ++c) {
        float zc = z[c];
#pragma unroll
        for (int j = 0; j < HID; ++j) d1[j] = fmaf(zc, Wd1[c * HID + j], d1[j]);
    }
#pragma unroll
    for (int j = 0; j < HID; ++j) d1[j] = fmaxf(d1[j], 0.0f);

    float d2[HID];
#pragma unroll
    for (int j = 0; j < HID; ++j) d2[j] = bd2[j];
#pragma unroll
    for (int c = 0; c < HID; ++c) {
        float dc = d1[c];
#pragma unroll
        for (int j = 0; j < HID; ++j) d2[j] = fmaf(dc, Wd2[c * HID + j], d2[j]);
    }

    float o = bd3[0];
#pragma unroll
    for (int j = 0; j < HID; ++j) o = fmaf(fmaxf(d2[j], 0.0f), Wd3[j], o);

    out[e] = 1.0f / (1.0f + expf(-o));
}

// ---------------------------------------------------------------------------
extern "C" void kernel_launch(void* const* d_in, const int* in_sizes, int n_in,
                              void* d_out, int out_size, void* d_ws, size_t ws_size,
                              hipStream_t stream) {
    const float* x      = (const float*)d_in[0];
    const int*   edge   = (const int*)d_in[1];   // (2, E): src then dst
    const int*   region = (const int*)d_in[2];
    const float* W_in1  = (const float*)d_in[3];
    const float* b_in1  = (const float*)d_in[4];
    const float* W_out1 = (const float*)d_in[5];
    const float* b_out1 = (const float*)d_in[6];
    const float* W_in2  = (const float*)d_in[7];
    const float* b_in2  = (const float*)d_in[8];
    const float* W_out2 = (const float*)d_in[9];
    const float* b_out2 = (const float*)d_in[10];
    const float* W_in3  = (const float*)d_in[11];
    const float* b_in3  = (const float*)d_in[12];
    const float* W_out3 = (const float*)d_in[13];
    const float* b_out3 = (const float*)d_in[14];
    const float* Wd1    = (const float*)d_in[15];
    const float* bd1    = (const float*)d_in[16];
    const float* Wd2    = (const float*)d_in[17];
    const float* bd2    = (const float*)d_in[18];
    const float* Wd3    = (const float*)d_in[19];
    const float* bd3    = (const float*)d_in[20];
    float* out = (float*)d_out;

    const int* src = edge;
    const int* dst = edge + N_EDGES;

    float* ws  = (float*)d_ws;
    float* hA  = ws;                     // N_NODES*16
    float* hB  = hA + N_NODES * HID;     // N_NODES*16
    float* agg = hB + N_NODES * HID;     // N_NODES*16
    float* cnt = agg + N_NODES * HID;    // N_NODES   (contiguous after agg)

    const int BLK = 256;
    const int egrid = (N_EDGES + BLK - 1) / BLK;
    const int ngrid = (N_NODES + BLK - 1) / BLK;

    // zero agg + cnt (contiguous region)
    hipMemsetAsync(agg, 0, (size_t)(N_NODES * HID + N_NODES) * sizeof(float), stream);

    degree_kernel<<<egrid, BLK, 0, stream>>>(dst, cnt);

    // layer 1: h from x columns 2..15 (stride 16)
    edge_msg_kernel<14><<<egrid, BLK, 0, stream>>>(x, x + 2, src, dst, region, W_in1, b_in1, agg);
    node_update_kernel<<<ngrid, BLK, 0, stream>>>(agg, cnt, W_out1, b_out1, hA);

    hipMemsetAsync(agg, 0, (size_t)(N_NODES * HID) * sizeof(float), stream);
    edge_msg_kernel<16><<<egrid, BLK, 0, stream>>>(x, hA, src, dst, region, W_in2, b_in2, agg);
    node_update_kernel<<<ngrid, BLK, 0, stream>>>(agg, cnt, W_out2, b_out2, hB);

    hipMemsetAsync(agg, 0, (size_t)(N_NODES * HID) * sizeof(float), stream);
    edge_msg_kernel<16><<<egrid, BLK, 0, stream>>>(x, hB, src, dst, region, W_in3, b_in3, agg);
    node_update_kernel<<<ngrid, BLK, 0, stream>>>(agg, cnt, W_out3, b_out3, hA);

    decoder_kernel<<<egrid, BLK, 0, stream>>>(hA, src, dst, Wd1, bd1, Wd2, bd2, Wd3, bd3, out);
}